// Round 1
// baseline (83.927 us; speedup 1.0000x reference)
//
#include <hip/hip_runtime.h>
#include <hip/hip_bf16.h>

// Speculative-decoding acceptance:
//   only rows r-1 .. L-1 (9 rows) of softmax(target_logits) are needed;
//   bulk of work = copying probs[:, :r, :] to output (memory-bound).
//
// Pipeline (all on `stream`):
//   1) row_stats_kernel  : per-row max / argmax / sumexp for rows 511..519 -> ws
//   2) accept_kernel     : n_match + id_res (521 floats) + n_match scalar -> out, ws
//   3) write_probs_kernel: prob_res rows (copy / masked softmax / zeros)  -> out

struct Ws {
    float mx[16];
    float sum[16];
    int   amax[16];
    int   n_match;
};

#define RS_BLK 256

__global__ void row_stats_kernel(const float* __restrict__ logits, Ws* __restrict__ ws,
                                 int V, int row0) {
    int j = blockIdx.x;
    const float* row = logits + (size_t)(row0 + j) * V;
    __shared__ float smax[RS_BLK];
    __shared__ int   sidx[RS_BLK];
    __shared__ float ssum[RS_BLK];
    int t = threadIdx.x;

    // pass 1: max + first-occurrence argmax
    float m = -INFINITY;
    int   mi = 0x7fffffff;
    for (int c = t; c < V; c += RS_BLK) {
        float v = row[c];
        if (v > m) { m = v; mi = c; }   // strict > keeps earliest index per-thread
    }
    smax[t] = m; sidx[t] = mi;
    __syncthreads();
    for (int s = RS_BLK >> 1; s > 0; s >>= 1) {
        if (t < s) {
            float vo = smax[t + s]; int io = sidx[t + s];
            if (vo > smax[t] || (vo == smax[t] && io < sidx[t])) {
                smax[t] = vo; sidx[t] = io;
            }
        }
        __syncthreads();
    }
    float gm = smax[0];

    // pass 2: sum of exp(x - max)  (row is L2-hot from pass 1)
    float acc = 0.0f;
    for (int c = t; c < V; c += RS_BLK) acc += expf(row[c] - gm);
    ssum[t] = acc;
    __syncthreads();
    for (int s = RS_BLK >> 1; s > 0; s >>= 1) {
        if (t < s) ssum[t] += ssum[t + s];
        __syncthreads();
    }
    if (t == 0) {
        ws->mx[j]   = gm;
        ws->sum[j]  = ssum[0];
        ws->amax[j] = sidx[0];
    }
}

__global__ void accept_kernel(const float* __restrict__ logits, const float* __restrict__ probs,
                              const int* __restrict__ ids, const int* __restrict__ leniency_p,
                              float* __restrict__ out, Ws* __restrict__ ws,
                              int V, int r, int K, long long out_last) {
    __shared__ int s_draft[16];
    __shared__ int s_acc[16];
    __shared__ int s_nm;
    int t = threadIdx.x;

    // id_res prefix: copy input_ids[:r] as float
    for (int i = t; i < r; i += blockDim.x) out[i] = (float)ids[i];

    if (t < K) {
        int dj = ids[r + t];                 // draft_ids[t]
        s_draft[t] = dj;
        size_t rowoff = (size_t)(r - 1 + t) * V;
        float tp = expf(logits[rowoff + dj] - ws->mx[t]) / ws->sum[t];
        float pp = probs[rowoff + dj];
        int   len = *leniency_p;
        bool eq      = (ws->amax[t] == dj);  // target_ids[t] == draft_ids[t]
        bool lenient = (len > 1) && (tp > pp / (float)len);
        s_acc[t] = (eq || lenient) ? 1 : 0;
    }
    __syncthreads();

    if (t == 0) {
        int nm = 0;
        for (int j = 0; j < K; j++) { if (s_acc[j]) nm++; else break; }
        s_nm = nm;
        ws->n_match = nm;
        out[out_last] = (float)nm;           // third output
    }
    __syncthreads();

    if (t <= K) {                            // new_ids positions 0..K
        int pos = t;
        int nm  = s_nm;
        int v;
        if (pos < nm)       v = s_draft[pos];   // pos < nm <= K so pos <= K-1
        else if (pos == nm) v = ws->amax[pos];  // target_ids[pos]
        else                v = 0;
        out[r + pos] = (float)v;
    }
}

#define PW_BLK 256
#define PW_EPT 4

__global__ void write_probs_kernel(const float* __restrict__ logits, const float* __restrict__ probs,
                                   float* __restrict__ out, const Ws* __restrict__ ws,
                                   int V, int r, long long prob_off) {
    int y = blockIdx.y;
    long long ob = prob_off + (long long)y * V;
    int c0 = blockIdx.x * (PW_BLK * PW_EPT) + threadIdx.x;

    if (y < r) {
        // straight copy of probs row y
        const float* src = probs + (size_t)y * V;
        #pragma unroll
        for (int k = 0; k < PW_EPT; k++) {
            int c = c0 + k * PW_BLK;
            if (c < V) out[ob + c] = src[c];
        }
    } else {
        int j = y - r;
        int nm = ws->n_match;
        if (j < nm) {
            // accepted row: softmax(target_logits[r-1+j])
            const float* lg = logits + (size_t)(r - 1 + j) * V;
            float m   = ws->mx[j];
            float inv = 1.0f / ws->sum[j];
            #pragma unroll
            for (int k = 0; k < PW_EPT; k++) {
                int c = c0 + k * PW_BLK;
                if (c < V) out[ob + c] = expf(lg[c] - m) * inv;
            }
        } else {
            #pragma unroll
            for (int k = 0; k < PW_EPT; k++) {
                int c = c0 + k * PW_BLK;
                if (c < V) out[ob + c] = 0.0f;
            }
        }
    }
}

extern "C" void kernel_launch(void* const* d_in, const int* in_sizes, int n_in,
                              void* d_out, int out_size, void* d_ws, size_t ws_size,
                              hipStream_t stream) {
    const float* logits     = (const float*)d_in[0];
    const float* probs      = (const float*)d_in[1];
    const int*   ids        = (const int*)d_in[2];
    const int*   leniency_p = (const int*)d_in[4];
    float* out = (float*)d_out;
    Ws*    ws  = (Ws*)d_ws;

    const int L = in_sizes[2];          // 520
    const int V = in_sizes[0] / L;      // 32128
    const int r = 512;                  // REVIEW_INDEX (problem compile-time constant)
    const int K = L - r;                // 8
    const long long prob_off = (long long)r + K + 1;   // 521
    const long long out_last = (long long)out_size - 1;

    // 1) stats for rows r-1 .. L-1  (K+1 = 9 rows)
    row_stats_kernel<<<K + 1, RS_BLK, 0, stream>>>(logits, ws, V, r - 1);

    // 2) n_match + id outputs
    accept_kernel<<<1, 512, 0, stream>>>(logits, probs, ids, leniency_p, out, ws,
                                         V, r, K, out_last);

    // 3) bulk prob_res writes
    int gx = (V + PW_BLK * PW_EPT - 1) / (PW_BLK * PW_EPT);
    dim3 grid(gx, L, 1);
    write_probs_kernel<<<grid, PW_BLK, 0, stream>>>(logits, probs, out, ws, V, r, prob_off);
}

// Round 2
// 38.512 us; speedup vs baseline: 2.1792x; 2.1792x over previous
//
#include <hip/hip_runtime.h>
#include <hip/hip_bf16.h>

// Speculative-decoding acceptance. R1 post-mortem: row_stats (9 blocks,
// 2-pass reduction) was 76.5/83.9 us at 0.37% occupancy. R2: single-pass
// online-softmax partials across 9 rows x 32 chunks (288 blocks, float4
// loads), merged by the 9 lead threads of accept_kernel.
//
// Pipeline (all on `stream`):
//   1) partial_stats_kernel: per-(row,chunk) online max/argmax/sumexp -> ws
//   2) accept_kernel       : merge partials; n_match + id_res -> out, ws
//   3) write_probs_kernel  : prob_res rows (copy / masked softmax / zeros)

#define NCHUNK 32
#define RS_BLK 256

struct Ws {
    float pmax[16][NCHUNK];
    float psum[16][NCHUNK];
    int   pidx[16][NCHUNK];
    float mx[16];
    float sum[16];
    int   amax[16];
    int   n_match;
};

struct MIS { float m; int i; float s; };

__device__ inline MIS mis_merge(MIS a, MIS b) {
    MIS r;
    r.i = (b.m > a.m || (b.m == a.m && b.i < a.i)) ? b.i : a.i;
    r.m = fmaxf(a.m, b.m);
    r.s = 0.0f;
    if (a.s > 0.0f) r.s += a.s * expf(a.m - r.m);   // guards nan from (-inf)-(-inf)
    if (b.s > 0.0f) r.s += b.s * expf(b.m - r.m);
    return r;
}

__global__ void partial_stats_kernel(const float* __restrict__ logits, Ws* __restrict__ ws,
                                     int V, int row0) {
    int j  = blockIdx.y;                       // row index 0..K
    int ch = blockIdx.x;                       // chunk 0..NCHUNK-1
    int chunk_elems = V / NCHUNK;              // 1004 (exact for V=32128)
    int nf4 = chunk_elems / 4;                 // 251 float4
    int cbase = ch * chunk_elems;
    const float4* row = (const float4*)(logits + (size_t)(row0 + j) * V + cbase);
    int t = threadIdx.x;

    // per-thread online softmax stats (first-occurrence argmax: strict >)
    float m = -INFINITY, s = 0.0f;
    int   idx = 0x7fffffff;
    for (int f = t; f < nf4; f += RS_BLK) {
        float4 v = row[f];
        float vv[4] = {v.x, v.y, v.z, v.w};
        int c = cbase + f * 4;
        #pragma unroll
        for (int u = 0; u < 4; u++) {
            float x = vv[u];
            if (x > m) { s = s * expf(m - x) + 1.0f; m = x; idx = c + u; }
            else       { s += expf(x - m); }
        }
    }

    __shared__ float sm[RS_BLK];
    __shared__ int   si[RS_BLK];
    __shared__ float ss[RS_BLK];
    sm[t] = m; si[t] = idx; ss[t] = s;
    __syncthreads();
    for (int w = RS_BLK >> 1; w > 0; w >>= 1) {
        if (t < w) {
            MIS a = {sm[t], si[t], ss[t]};
            MIS b = {sm[t + w], si[t + w], ss[t + w]};
            MIS r = mis_merge(a, b);
            sm[t] = r.m; si[t] = r.i; ss[t] = r.s;
        }
        __syncthreads();
    }
    if (t == 0) {
        ws->pmax[j][ch] = sm[0];
        ws->psum[j][ch] = ss[0];
        ws->pidx[j][ch] = si[0];
    }
}

__global__ void accept_kernel(const float* __restrict__ logits, const float* __restrict__ probs,
                              const int* __restrict__ ids, const int* __restrict__ leniency_p,
                              float* __restrict__ out, Ws* __restrict__ ws,
                              int V, int r, int K, long long out_last) {
    __shared__ int s_draft[16];
    __shared__ int s_acc[16];
    __shared__ int s_nm;
    int t = threadIdx.x;

    // merge the NCHUNK partials for rows 0..K
    if (t <= K) {
        MIS acc = {ws->pmax[t][0], ws->pidx[t][0], ws->psum[t][0]};
        for (int c = 1; c < NCHUNK; c++) {
            MIS b = {ws->pmax[t][c], ws->pidx[t][c], ws->psum[t][c]};
            acc = mis_merge(acc, b);
        }
        ws->mx[t] = acc.m; ws->sum[t] = acc.s; ws->amax[t] = acc.i;
    }
    __syncthreads();

    // id_res prefix: input_ids[:r] as float
    for (int i = t; i < r; i += blockDim.x) out[i] = (float)ids[i];

    if (t < K) {
        int dj = ids[r + t];                 // draft_ids[t]
        s_draft[t] = dj;
        size_t rowoff = (size_t)(r - 1 + t) * V;
        float tp = expf(logits[rowoff + dj] - ws->mx[t]) / ws->sum[t];
        float pp = probs[rowoff + dj];
        int   len = *leniency_p;
        bool eq      = (ws->amax[t] == dj);  // target_ids[t] == draft_ids[t]
        bool lenient = (len > 1) && (tp > pp / (float)len);
        s_acc[t] = (eq || lenient) ? 1 : 0;
    }
    __syncthreads();

    if (t == 0) {
        int nm = 0;
        for (int j = 0; j < K; j++) { if (s_acc[j]) nm++; else break; }
        s_nm = nm;
        ws->n_match = nm;
        out[out_last] = (float)nm;           // third output
    }
    __syncthreads();

    if (t <= K) {                            // new_ids positions 0..K
        int pos = t;
        int nm  = s_nm;
        int v;
        if (pos < nm)       v = s_draft[pos];
        else if (pos == nm) v = ws->amax[pos];
        else                v = 0;
        out[r + pos] = (float)v;
    }
}

#define PW_BLK 256
#define PW_EPT 4

__global__ void write_probs_kernel(const float* __restrict__ logits, const float* __restrict__ probs,
                                   float* __restrict__ out, const Ws* __restrict__ ws,
                                   int V, int r, long long prob_off) {
    int y = blockIdx.y;
    long long ob = prob_off + (long long)y * V;
    int c0 = blockIdx.x * (PW_BLK * PW_EPT) + threadIdx.x;

    if (y < r) {
        const float* src = probs + (size_t)y * V;
        #pragma unroll
        for (int k = 0; k < PW_EPT; k++) {
            int c = c0 + k * PW_BLK;
            if (c < V) out[ob + c] = src[c];
        }
    } else {
        int j = y - r;
        int nm = ws->n_match;
        if (j < nm) {
            const float* lg = logits + (size_t)(r - 1 + j) * V;
            float m   = ws->mx[j];
            float inv = 1.0f / ws->sum[j];
            #pragma unroll
            for (int k = 0; k < PW_EPT; k++) {
                int c = c0 + k * PW_BLK;
                if (c < V) out[ob + c] = expf(lg[c] - m) * inv;
            }
        } else {
            #pragma unroll
            for (int k = 0; k < PW_EPT; k++) {
                int c = c0 + k * PW_BLK;
                if (c < V) out[ob + c] = 0.0f;
            }
        }
    }
}

extern "C" void kernel_launch(void* const* d_in, const int* in_sizes, int n_in,
                              void* d_out, int out_size, void* d_ws, size_t ws_size,
                              hipStream_t stream) {
    const float* logits     = (const float*)d_in[0];
    const float* probs      = (const float*)d_in[1];
    const int*   ids        = (const int*)d_in[2];
    const int*   leniency_p = (const int*)d_in[4];
    float* out = (float*)d_out;
    Ws*    ws  = (Ws*)d_ws;

    const int L = in_sizes[2];          // 520
    const int V = in_sizes[0] / L;      // 32128
    const int r = 512;                  // REVIEW_INDEX (problem constant)
    const int K = L - r;                // 8
    const long long prob_off = (long long)r + K + 1;   // 521
    const long long out_last = (long long)out_size - 1;

    // 1) partial stats for rows r-1 .. L-1  (K+1 = 9 rows x NCHUNK chunks)
    dim3 g1(NCHUNK, K + 1, 1);
    partial_stats_kernel<<<g1, RS_BLK, 0, stream>>>(logits, ws, V, r - 1);

    // 2) merge + n_match + id outputs
    accept_kernel<<<1, 512, 0, stream>>>(logits, probs, ids, leniency_p, out, ws,
                                         V, r, K, out_last);

    // 3) bulk prob_res writes
    int gx = (V + PW_BLK * PW_EPT - 1) / (PW_BLK * PW_EPT);
    dim3 grid(gx, L, 1);
    write_probs_kernel<<<grid, PW_BLK, 0, stream>>>(logits, probs, out, ws, V, r, prob_off);
}

// Round 3
// 34.790 us; speedup vs baseline: 2.4124x; 1.1070x over previous
//
#include <hip/hip_runtime.h>
#include <hip/hip_bf16.h>

// Speculative-decoding acceptance. R2 post-mortem: 38.5us total vs ~21us
// traffic floor (134 MB). R3: (1) fuse the 512-row copy with the 9-row
// stats into one grid (stats hide under copy), (2) dst-aligned float4
// stores + 4B-aligned float4 loads for the copy (out rows start at
// element 521+y*V == 1 mod 4: 3-elem head + aligned body + 1 tail).
//
// Pipeline: fused_copy_stats -> accept_kernel -> tail_probs_kernel

#define NCHUNK 32
#define BLK 256
#define CP_EPT 8   // float4 per thread in copy body

struct Ws {
    float pmax[16][NCHUNK];
    float psum[16][NCHUNK];
    int   pidx[16][NCHUNK];
    float mx[16];
    float sum[16];
    int   amax[16];
    int   n_match;
};

struct MIS { float m; int i; float s; };

__device__ inline MIS mis_merge(MIS a, MIS b) {
    MIS r;
    r.i = (b.m > a.m || (b.m == a.m && b.i < a.i)) ? b.i : a.i;
    r.m = fmaxf(a.m, b.m);
    r.s = 0.0f;
    if (a.s > 0.0f) r.s += a.s * expf(a.m - r.m);   // guard nan from (-inf)-(-inf)
    if (b.s > 0.0f) r.s += b.s * expf(b.m - r.m);
    return r;
}

// 4-byte-aligned float4 for unaligned-src loads (gfx9+ handles unaligned global)
typedef float f4u __attribute__((ext_vector_type(4), aligned(4)));

__global__ void fused_copy_stats(const float* __restrict__ logits,
                                 const float* __restrict__ probs,
                                 float* __restrict__ out, Ws* __restrict__ ws,
                                 int V, int row0, long long prob_off,
                                 int nCopyBlocks, int blocksPerRow, int nf4) {
    int t = threadIdx.x;

    if ((int)blockIdx.x < nCopyBlocks) {
        // ---- copy path: out[prob_off + y*V + c] = probs[y*V + c], rows 0..r-1
        int y   = blockIdx.x / blocksPerRow;
        int sub = blockIdx.x % blocksPerRow;
        const float* src = probs + (size_t)y * V;
        float*       dst = out + prob_off + (size_t)y * V;   // element ≡1 mod 4

        if (sub == 0) {
            if (t < 3)       dst[t] = src[t];        // head c=0,1,2
            else if (t == 3) dst[V - 1] = src[V - 1]; // tail c=V-1
        }
        int f0 = sub * (BLK * CP_EPT) + t;
        #pragma unroll
        for (int k = 0; k < CP_EPT; k++) {
            int f = f0 + k * BLK;
            if (f < nf4) {
                f4u v = *reinterpret_cast<const f4u*>(src + 3 + 4 * f);
                *reinterpret_cast<float4*>(dst + 3 + 4 * f) =
                    float4{v.x, v.y, v.z, v.w};      // dst+3 is 16B-aligned
            }
        }
        return;
    }

    // ---- stats path: per-(row,chunk) online softmax partials
    int idx = blockIdx.x - nCopyBlocks;
    int ch = idx & (NCHUNK - 1);
    int j  = idx / NCHUNK;
    int chunk_elems = V / NCHUNK;                  // 1004
    int cf4 = chunk_elems / 4;                     // 251
    int cbase = ch * chunk_elems;
    const float4* row = (const float4*)(logits + (size_t)(row0 + j) * V + cbase);

    float m = -INFINITY, s = 0.0f;
    int   mi = 0x7fffffff;
    for (int f = t; f < cf4; f += BLK) {
        float4 v = row[f];
        float vv[4] = {v.x, v.y, v.z, v.w};
        int c = cbase + f * 4;
        #pragma unroll
        for (int u = 0; u < 4; u++) {
            float x = vv[u];
            if (x > m) { s = s * expf(m - x) + 1.0f; m = x; mi = c + u; }
            else       { s += expf(x - m); }
        }
    }

    __shared__ float sm[BLK];
    __shared__ int   si[BLK];
    __shared__ float ss[BLK];
    sm[t] = m; si[t] = mi; ss[t] = s;
    __syncthreads();
    for (int w = BLK >> 1; w > 0; w >>= 1) {
        if (t < w) {
            MIS a = {sm[t], si[t], ss[t]};
            MIS b = {sm[t + w], si[t + w], ss[t + w]};
            MIS rr = mis_merge(a, b);
            sm[t] = rr.m; si[t] = rr.i; ss[t] = rr.s;
        }
        __syncthreads();
    }
    if (t == 0) {
        ws->pmax[j][ch] = sm[0];
        ws->psum[j][ch] = ss[0];
        ws->pidx[j][ch] = si[0];
    }
}

__global__ void accept_kernel(const float* __restrict__ logits, const float* __restrict__ probs,
                              const int* __restrict__ ids, const int* __restrict__ leniency_p,
                              float* __restrict__ out, Ws* __restrict__ ws,
                              int V, int r, int K, long long out_last) {
    __shared__ int s_draft[16];
    __shared__ int s_acc[16];
    __shared__ int s_nm;
    int t = threadIdx.x;

    if (t <= K) {                                  // merge NCHUNK partials
        MIS acc = {ws->pmax[t][0], ws->pidx[t][0], ws->psum[t][0]};
        for (int c = 1; c < NCHUNK; c++) {
            MIS b = {ws->pmax[t][c], ws->pidx[t][c], ws->psum[t][c]};
            acc = mis_merge(acc, b);
        }
        ws->mx[t] = acc.m; ws->sum[t] = acc.s; ws->amax[t] = acc.i;
    }
    __syncthreads();

    for (int i = t; i < r; i += blockDim.x) out[i] = (float)ids[i];  // id prefix

    if (t < K) {
        int dj = ids[r + t];
        s_draft[t] = dj;
        size_t rowoff = (size_t)(r - 1 + t) * V;
        float tp = expf(logits[rowoff + dj] - ws->mx[t]) / ws->sum[t];
        float pp = probs[rowoff + dj];
        int   len = *leniency_p;
        bool eq      = (ws->amax[t] == dj);
        bool lenient = (len > 1) && (tp > pp / (float)len);
        s_acc[t] = (eq || lenient) ? 1 : 0;
    }
    __syncthreads();

    if (t == 0) {
        int nm = 0;
        for (int j = 0; j < K; j++) { if (s_acc[j]) nm++; else break; }
        s_nm = nm;
        ws->n_match = nm;
        out[out_last] = (float)nm;
    }
    __syncthreads();

    if (t <= K) {
        int pos = t, nm = s_nm, v;
        if (pos < nm)       v = s_draft[pos];
        else if (pos == nm) v = ws->amax[pos];
        else                v = 0;
        out[r + pos] = (float)v;
    }
}

#define TP_EPT 4

__global__ void tail_probs_kernel(const float* __restrict__ logits,
                                  float* __restrict__ out, const Ws* __restrict__ ws,
                                  int V, int r, long long prob_off) {
    int j = blockIdx.y;                            // 0..K-1, row y = r+j
    long long ob = prob_off + (long long)(r + j) * V;
    int c0 = blockIdx.x * (BLK * TP_EPT) + threadIdx.x;
    int nm = ws->n_match;

    if (j < nm) {
        const float* lg = logits + (size_t)(r - 1 + j) * V;
        float m   = ws->mx[j];
        float inv = 1.0f / ws->sum[j];
        #pragma unroll
        for (int k = 0; k < TP_EPT; k++) {
            int c = c0 + k * BLK;
            if (c < V) out[ob + c] = expf(lg[c] - m) * inv;
        }
    } else {
        #pragma unroll
        for (int k = 0; k < TP_EPT; k++) {
            int c = c0 + k * BLK;
            if (c < V) out[ob + c] = 0.0f;
        }
    }
}

extern "C" void kernel_launch(void* const* d_in, const int* in_sizes, int n_in,
                              void* d_out, int out_size, void* d_ws, size_t ws_size,
                              hipStream_t stream) {
    const float* logits     = (const float*)d_in[0];
    const float* probs      = (const float*)d_in[1];
    const int*   ids        = (const int*)d_in[2];
    const int*   leniency_p = (const int*)d_in[4];
    float* out = (float*)d_out;
    Ws*    ws  = (Ws*)d_ws;

    const int L = in_sizes[2];          // 520
    const int V = in_sizes[0] / L;      // 32128
    const int r = 512;                  // REVIEW_INDEX (problem constant)
    const int K = L - r;                // 8
    const long long prob_off = (long long)r + K + 1;   // 521
    const long long out_last = (long long)out_size - 1;

    const int nf4 = (V - 4) / 4;                       // 8031 aligned float4/row
    const int blocksPerRow = (nf4 + BLK * CP_EPT - 1) / (BLK * CP_EPT);  // 4
    const int nCopyBlocks  = r * blocksPerRow;                           // 2048
    const int nStatsBlocks = (K + 1) * NCHUNK;                           // 288

    // 1) fused copy (rows 0..r-1) + stats (rows r-1..L-1 partials)
    fused_copy_stats<<<nCopyBlocks + nStatsBlocks, BLK, 0, stream>>>(
        logits, probs, out, ws, V, r - 1, prob_off, nCopyBlocks, blocksPerRow, nf4);

    // 2) merge + n_match + id outputs
    accept_kernel<<<1, 512, 0, stream>>>(logits, probs, ids, leniency_p, out, ws,
                                         V, r, K, out_last);

    // 3) n_match-dependent tail rows (8 rows)
    dim3 g3((V + BLK * TP_EPT - 1) / (BLK * TP_EPT), K, 1);
    tail_probs_kernel<<<g3, BLK, 0, stream>>>(logits, out, ws, V, r, prob_off);
}

// Round 4
// 33.706 us; speedup vs baseline: 2.4900x; 1.0322x over previous
//
#include <hip/hip_runtime.h>
#include <hip/hip_bf16.h>

// Speculative-decoding acceptance. R3 post-mortem: fused copy ran at ~5 TB/s
// effective vs 6.8 TB/s fill-kernel ceiling; accept+tail launches ~5us.
// R4: (1) nontemporal stores for all bulk out-writes (out never re-read ->
// keep probs/logits L3-resident), (2) drop accept_kernel: tail blocks
// self-merge the stats partials redundantly, (3) flat contiguous copy.
//
// Pipeline: fused_copy_stats -> tail_kernel   (2 dispatches)

#define NCHUNK 32
#define BLK 256
#define NSTATS ((8 + 1) * NCHUNK)     // 288 stats blocks (K+1=9 rows)
#define GRID1 2048                    // co-resident at 256 thr, low VGPR
#define NCOPY (GRID1 - NSTATS - 1)    // 1759 copy blocks, 1 id block

struct Ws {
    float pmax[16][NCHUNK];
    float psum[16][NCHUNK];
    int   pidx[16][NCHUNK];
};

struct MIS { float m; int i; float s; };

__device__ inline MIS mis_merge(MIS a, MIS b) {
    MIS r;
    r.i = (b.m > a.m || (b.m == a.m && b.i < a.i)) ? b.i : a.i;
    r.m = fmaxf(a.m, b.m);
    r.s = 0.0f;
    if (a.s > 0.0f) r.s += a.s * expf(a.m - r.m);   // guard nan from (-inf)-(-inf)
    if (b.s > 0.0f) r.s += b.s * expf(b.m - r.m);
    return r;
}

typedef float f4  __attribute__((ext_vector_type(4)));               // 16B-aligned
typedef float f4u __attribute__((ext_vector_type(4), aligned(4)));   // unaligned-src

__global__ void fused_copy_stats(const float* __restrict__ logits,
                                 const float* __restrict__ probs,
                                 const int* __restrict__ ids,
                                 float* __restrict__ out, Ws* __restrict__ ws,
                                 int V, int r, long long prob_off, int nf4) {
    int t = threadIdx.x;
    int b = blockIdx.x;

    if (b < NCOPY) {
        // ---- flat copy: probs[0 .. r*V) -> out[prob_off ..), dst+3 16B-aligned
        const float* src = probs + 3;
        float*       dst = out + prob_off + 3;
        for (int i = b * BLK + t; i < nf4; i += NCOPY * BLK) {
            f4u v = *reinterpret_cast<const f4u*>(src + 4 * (size_t)i);
            __builtin_nontemporal_store((f4)v, reinterpret_cast<f4*>(dst + 4 * (size_t)i));
        }
        return;
    }

    if (b < NCOPY + NSTATS) {
        // ---- stats: per-(row,chunk) online softmax partials, rows r-1..r+K-1+1
        int idx = b - NCOPY;
        int ch = idx & (NCHUNK - 1);
        int j  = idx / NCHUNK;
        int chunk_elems = V / NCHUNK;              // 1004
        int cf4 = chunk_elems / 4;                 // 251
        int cbase = ch * chunk_elems;
        const float4* row = (const float4*)(logits + (size_t)(r - 1 + j) * V + cbase);

        float m = -INFINITY, s = 0.0f;
        int   mi = 0x7fffffff;
        for (int f = t; f < cf4; f += BLK) {
            float4 v = row[f];
            float vv[4] = {v.x, v.y, v.z, v.w};
            int c = cbase + f * 4;
            #pragma unroll
            for (int u = 0; u < 4; u++) {
                float x = vv[u];
                if (x > m) { s = s * expf(m - x) + 1.0f; m = x; mi = c + u; }
                else       { s += expf(x - m); }
            }
        }

        __shared__ float sm[BLK];
        __shared__ int   si[BLK];
        __shared__ float ss[BLK];
        sm[t] = m; si[t] = mi; ss[t] = s;
        __syncthreads();
        for (int w = BLK >> 1; w > 0; w >>= 1) {
            if (t < w) {
                MIS a = {sm[t], si[t], ss[t]};
                MIS bb = {sm[t + w], si[t + w], ss[t + w]};
                MIS rr = mis_merge(a, bb);
                sm[t] = rr.m; si[t] = rr.i; ss[t] = rr.s;
            }
            __syncthreads();
        }
        if (t == 0) {
            ws->pmax[j][ch] = sm[0];
            ws->psum[j][ch] = ss[0];
            ws->pidx[j][ch] = si[0];
        }
        return;
    }

    // ---- last block: id prefix + copy head/tail
    for (int i = t; i < r; i += BLK) out[i] = (float)ids[i];
    if (t < 3)       out[prob_off + t] = probs[t];                 // head 0,1,2
    else if (t == 3) {
        long long last = (long long)r * V - 1;                     // copy tail elem
        out[prob_off + last] = probs[last];
    }
}

#define TP_EPT 8

__global__ void tail_kernel(const float* __restrict__ logits, const float* __restrict__ probs,
                            const int* __restrict__ ids, const int* __restrict__ leniency_p,
                            float* __restrict__ out, const Ws* __restrict__ ws,
                            int V, int r, int K, long long prob_off, long long out_last) {
    __shared__ float s_mx[12];
    __shared__ float s_sum[12];
    __shared__ int   s_amax[12];
    __shared__ int   s_draft[12];
    __shared__ int   s_acc[12];
    __shared__ int   s_nm;
    int t = threadIdx.x;
    int j   = blockIdx.y;              // tail row 0..K-1 (out row r+j)
    int sub = blockIdx.x;

    // self-merge the NCHUNK partials for rows 0..K (redundant per block; ws is L2-hot)
    if (t <= K) {
        MIS acc = {ws->pmax[t][0], ws->pidx[t][0], ws->psum[t][0]};
        for (int c = 1; c < NCHUNK; c++) {
            MIS bb = {ws->pmax[t][c], ws->pidx[t][c], ws->psum[t][c]};
            acc = mis_merge(acc, bb);
        }
        s_mx[t] = acc.m; s_sum[t] = acc.s; s_amax[t] = acc.i;
    }
    __syncthreads();

    if (t < K) {
        int dj = ids[r + t];
        s_draft[t] = dj;
        size_t rowoff = (size_t)(r - 1 + t) * V;
        float tp = expf(logits[rowoff + dj] - s_mx[t]) / s_sum[t];
        float pp = probs[rowoff + dj];
        int   len = *leniency_p;
        bool eq      = (s_amax[t] == dj);
        bool lenient = (len > 1) && (tp > pp / (float)len);
        s_acc[t] = (eq || lenient) ? 1 : 0;
    }
    __syncthreads();

    if (t == 0) {
        int nm = 0;
        for (int q = 0; q < K; q++) { if (s_acc[q]) nm++; else break; }
        s_nm = nm;
    }
    __syncthreads();
    int nm = s_nm;

    // designated block writes new_ids + n_match scalar
    if (j == 0 && sub == 0) {
        if (t <= K) {
            int v;
            if (t < nm)       v = s_draft[t];
            else if (t == nm) v = s_amax[t];
            else              v = 0;
            out[r + t] = (float)v;
        }
        if (t == K + 1) out[out_last] = (float)nm;
    }

    // write tail row r+j : softmax(logits row r-1+j) if accepted, else zeros
    long long ob = prob_off + (long long)(r + j) * V;   // ob % 4 == 1
    const float* lg = logits + (size_t)(r - 1 + j) * V;
    bool on = (j < nm);
    float m   = s_mx[j];
    float inv = on ? (1.0f / s_sum[j]) : 0.0f;

    if (sub == 0) {                                     // head 0,1,2 + tail V-1
        if (t < 3)       out[ob + t]     = on ? expf(lg[t] - m) * inv : 0.0f;
        else if (t == 3) out[ob + V - 1] = on ? expf(lg[V - 1] - m) * inv : 0.0f;
    }
    int nf4r = (V - 4) / 4;                             // 8031
    float* dst = out + ob + 3;
    const float* srcl = lg + 3;
    #pragma unroll
    for (int k = 0; k < TP_EPT; k++) {
        int i = sub * (BLK * TP_EPT) + t + k * BLK;
        if (i < nf4r) {
            f4 v;
            if (on) {
                f4u x = *reinterpret_cast<const f4u*>(srcl + 4 * (size_t)i);
                v.x = expf(x.x - m) * inv; v.y = expf(x.y - m) * inv;
                v.z = expf(x.z - m) * inv; v.w = expf(x.w - m) * inv;
            } else {
                v = (f4)0.0f;
            }
            __builtin_nontemporal_store(v, reinterpret_cast<f4*>(dst + 4 * (size_t)i));
        }
    }
}

extern "C" void kernel_launch(void* const* d_in, const int* in_sizes, int n_in,
                              void* d_out, int out_size, void* d_ws, size_t ws_size,
                              hipStream_t stream) {
    const float* logits     = (const float*)d_in[0];
    const float* probs      = (const float*)d_in[1];
    const int*   ids        = (const int*)d_in[2];
    const int*   leniency_p = (const int*)d_in[4];
    float* out = (float*)d_out;
    Ws*    ws  = (Ws*)d_ws;

    const int L = in_sizes[2];          // 520
    const int V = in_sizes[0] / L;      // 32128
    const int r = 512;                  // REVIEW_INDEX (problem constant)
    const int K = L - r;                // 8
    const long long prob_off = (long long)r + K + 1;   // 521
    const long long out_last = (long long)out_size - 1;

    const long long N = (long long)r * V;              // flat copy length
    const int nf4 = (int)((N - 3) / 4);                // aligned float4 count

    // 1) flat copy + stats partials + id prefix (one grid)
    fused_copy_stats<<<GRID1, BLK, 0, stream>>>(logits, probs, ids, out, ws,
                                                V, r, prob_off, nf4);

    // 2) self-merge accept + tail rows + new_ids + n_match
    dim3 g2((V / 4 + BLK * TP_EPT - 1) / (BLK * TP_EPT), K, 1);   // (4, 8)
    tail_kernel<<<g2, BLK, 0, stream>>>(logits, probs, ids, leniency_p, out, ws,
                                        V, r, K, prob_off, out_last);
}